// Round 1
// baseline (441.670 us; speedup 1.0000x reference)
//
#include <hip/hip_runtime.h>
#include <math.h>

// Problem constants (B,N,K,C,H,W) = (2,8,8,256,96,96)
constexpr int Bc = 2, Nc = 8, Kc = 8, Cc = 256, HWc = 96 * 96;   // HW = 9216
constexpr int BN = Bc * Nc;                                       // 16
constexpr float ALPHA = 0.3f;
constexpr float SIM_HIGH = 0.8f, SIM_LOW = 0.3f;

// ---------------- reduction helpers (blockDim.x == 256, 4 waves) -----------
__device__ __forceinline__ float wred_sum(float v) {
#pragma unroll
  for (int o = 32; o > 0; o >>= 1) v += __shfl_down(v, o, 64);
  return v;
}
__device__ __forceinline__ float wred_max(float v) {
#pragma unroll
  for (int o = 32; o > 0; o >>= 1) v = fmaxf(v, __shfl_down(v, o, 64));
  return v;
}
__device__ __forceinline__ float bred_sum(float v, float* sc) {
  int lane = threadIdx.x & 63, wid = threadIdx.x >> 6;
  v = wred_sum(v);
  __syncthreads();
  if (lane == 0) sc[wid] = v;
  __syncthreads();
  return sc[0] + sc[1] + sc[2] + sc[3];
}
__device__ __forceinline__ float bred_max(float v, float* sc) {
  int lane = threadIdx.x & 63, wid = threadIdx.x >> 6;
  v = wred_max(v);
  __syncthreads();
  if (lane == 0) sc[wid] = v;
  __syncthreads();
  return fmaxf(fmaxf(sc[0], sc[1]), fmaxf(sc[2], sc[3]));
}

// ---------------- K1: per-(b,n,c) sums of value and value*mask -------------
// grid = BN*Cc (4096) blocks, 256 threads; float4 streaming (16 B/lane).
__global__ __launch_bounds__(256) void k1_sums(const float* __restrict__ value,
                                               const float* __restrict__ mask,
                                               float* __restrict__ sum_v,
                                               float* __restrict__ sum_vm) {
  const int bnc = blockIdx.x;      // (b*N+n)*C + c
  const int bn = bnc >> 8;
  const int tid = threadIdx.x;
  const float4* v4 = (const float4*)(value + (size_t)bnc * HWc);
  const float4* m4 = (const float4*)(mask + (size_t)bn * HWc);
  float av = 0.f, avm = 0.f;
#pragma unroll
  for (int i = 0; i < 9; ++i) {              // 9*256*4 = 9216
    float4 v = v4[i * 256 + tid];
    float4 m = m4[i * 256 + tid];
    av += v.x + v.y + v.z + v.w;
    avm += v.x * m.x + v.y * m.y + v.z * m.z + v.w * m.w;
  }
  __shared__ float sc[8];
  float rv = wred_sum(av);
  float rvm = wred_sum(avm);
  int lane = tid & 63, wid = tid >> 6;
  if (lane == 0) { sc[wid] = rv; sc[4 + wid] = rvm; }
  __syncthreads();
  if (tid == 0) {
    sum_v[bnc] = sc[0] + sc[1] + sc[2] + sc[3];
    sum_vm[bnc] = sc[4] + sc[5] + sc[6] + sc[7];
  }
}

// ---------------- K2: control logic + bank update (1 block per (b,n)) ------
__global__ __launch_bounds__(256) void k2_update(
    const float* __restrict__ mask, const float* __restrict__ proto,
    const float* __restrict__ age, const float* __restrict__ usage,
    const float* __restrict__ conf, const int* __restrict__ valid,
    const float* __restrict__ sum_v, const float* __restrict__ sum_vm,
    float* __restrict__ proto_new, float* __restrict__ bank_nn,
    float* __restrict__ validf) {
  const int bn = blockIdx.x;
  const int tid = threadIdx.x;
  __shared__ float sc[4];
  __shared__ float s_cand[Cc];
  __shared__ float s_sim[Kc];
  __shared__ int s_slot, s_ref, s_wr;

  // global (over all B,N,K) maxima for age_n / usage_n
  float a = (tid < BN * Kc) ? age[tid] : -3e38f;
  float u = (tid < BN * Kc) ? usage[tid] : -3e38f;
  const float age_den = fmaxf(bred_max(a, sc), 1.0f);
  const float usage_den = fmaxf(bred_max(u, sc), 1.0f);

  // mask sum for this (b,n)
  float ms = 0.f;
  const float* mrow = mask + (size_t)bn * HWc;
  for (int i = tid; i < HWc; i += 256) ms += mrow[i];
  const float msum = bred_sum(ms, sc);
  const float denom = fmaxf(msum, 1e-6f);

  // candidate prototype (c = tid), l2-normalized
  const int c = tid;
  const float sv = sum_v[bn * Cc + c];
  const float svm = sum_vm[bn * Cc + c];
  float cand = (denom <= 1e-5f) ? (sv * (1.0f / HWc)) : (svm / denom);
  const float css = bred_sum(cand * cand, sc);
  const float cn = cand / fmaxf(sqrtf(css), 1e-12f);
  s_cand[c] = cn;
  __syncthreads();

  // sim[k] = dot(cand_n, proto_k / ||proto_k||), masked by valid
  for (int k = 0; k < Kc; ++k) {
    const float p = proto[((size_t)bn * Kc + k) * Cc + c];
    const float pss = bred_sum(p * p, sc);
    const float pn = fmaxf(sqrtf(pss), 1e-12f);
    const float d = bred_sum(s_cand[c] * p, sc);
    if (tid == 0) s_sim[k] = (valid[bn * Kc + k] != 0) ? (d / pn) : -1.0f;
  }
  __syncthreads();

  if (tid == 0) {
    bool anyv = false;
    for (int k = 0; k < Kc; ++k) anyv = anyv || (valid[bn * Kc + k] != 0);
    int tslot = 0; float best = s_sim[0];
    for (int k = 1; k < Kc; ++k)
      if (s_sim[k] > best) { best = s_sim[k]; tslot = k; }   // first max
    const float max_sim = anyv ? best : -1.0f;
    // action: 0=KEEP 1=REFINE 3=SPAWN
    const int action = (!anyv) ? 3 : (max_sim >= SIM_HIGH ? 1 : (max_sim >= SIM_LOW ? 0 : 3));
    // victim = argmax(age_n + (1-usage_n) + (1-conf)), first max
    int victim = 0; float vb = -3e38f;
    for (int k = 0; k < Kc; ++k) {
      const float s = age[bn * Kc + k] / age_den + (1.f - usage[bn * Kc + k] / usage_den) +
                      (1.f - conf[bn * Kc + k]);
      if (s > vb) { vb = s; victim = k; }
    }
    int fe = 0; bool hasE = false;
    for (int k = 0; k < Kc; ++k)
      if (valid[bn * Kc + k] == 0) { fe = k; hasE = true; break; }
    const int spawn = hasE ? fe : victim;
    s_slot = (action == 1) ? tslot : spawn;
    s_ref = (action == 1);
    s_wr = (action == 3);
  }
  __syncthreads();

  // bank update + pre-normalized bank (branches are block-uniform)
  for (int k = 0; k < Kc; ++k) {
    const float p = proto[((size_t)bn * Kc + k) * Cc + c];
    float pnew;
    if (k == s_slot && s_ref) {
      const float t = (1.0f - ALPHA) * p + ALPHA * s_cand[c];
      const float tss = bred_sum(t * t, sc);
      pnew = t / fmaxf(sqrtf(tss), 1e-12f);
    } else if (k == s_slot && s_wr) {
      pnew = s_cand[c];
    } else {
      pnew = p;
    }
    proto_new[((size_t)bn * Kc + k) * Cc + c] = pnew;
    const float bss = bred_sum(pnew * pnew, sc);
    bank_nn[((size_t)bn * Kc + k) * Cc + c] = pnew / fmaxf(sqrtf(bss), 1e-12f);
  }
  if (tid < Kc) {
    const int k = tid;
    const int vn = (valid[bn * Kc + k] != 0) || (s_wr && k == s_slot);
    validf[bn * Kc + k] = vn ? 1.0f : 0.0f;
  }
}

// ---------------- K3: readout (softmax-attention blend) --------------------
// grid = BN*36 (576) blocks, 128 threads, 2 hw positions/thread (float2).
__global__ __launch_bounds__(128) void k3_readout(
    const float* __restrict__ value, const float* __restrict__ frame,
    const float* __restrict__ proto_new, const float* __restrict__ bank_nn,
    const float* __restrict__ validf, const float* __restrict__ pgp,
    const float* __restrict__ fgp, float* __restrict__ out) {
  const int bn = blockIdx.x / 36;
  const int tile = blockIdx.x % 36;
  const int b = bn >> 3;
  const int tid = threadIdx.x;
  const int p2 = tile * 128 + tid;           // float2 index, HW/2 = 4608 total

  __shared__ float s_bank[Kc * Cc];          // [c][k] for b128 broadcast reads
  __shared__ float s_pn[Kc * Cc];            // [c][k]
  __shared__ float s_vld[Kc];

  const float* bsrc = bank_nn + (size_t)bn * Kc * Cc;
  const float* psrc = proto_new + (size_t)bn * Kc * Cc;
  for (int i = tid; i < Kc * Cc; i += 128) {
    const int k = i >> 8, c = i & 255;
    s_bank[c * 8 + k] = bsrc[i];
    s_pn[c * 8 + k] = psrc[i];
  }
  if (tid < Kc) s_vld[tid] = validf[bn * Kc + tid];
  __syncthreads();

  const float pg = pgp[0], fg = fgp[0];
  const float2* v2 = (const float2*)(value + (size_t)bn * Cc * HWc);
  const float2* f2 = (const float2*)(frame + (size_t)b * Cc * HWc);
  float2* o2 = (float2*)(out + (size_t)bn * Cc * HWc);
  const float4* bk4 = (const float4*)s_bank;
  const float4* pn4 = (const float4*)s_pn;
  constexpr int HW2 = HWc / 2;

  // pass 1: channel norms + 8 dots per position
  float ss0 = 0.f, ss1 = 0.f;
  float d0[8], d1[8];
#pragma unroll
  for (int k = 0; k < 8; ++k) { d0[k] = 0.f; d1[k] = 0.f; }

#pragma unroll 8
  for (int c = 0; c < Cc; ++c) {
    const float2 v = v2[c * HW2 + p2];
    const float4 ba = bk4[c * 2 + 0];
    const float4 bb = bk4[c * 2 + 1];
    ss0 += v.x * v.x; ss1 += v.y * v.y;
    d0[0] += ba.x * v.x; d0[1] += ba.y * v.x; d0[2] += ba.z * v.x; d0[3] += ba.w * v.x;
    d0[4] += bb.x * v.x; d0[5] += bb.y * v.x; d0[6] += bb.z * v.x; d0[7] += bb.w * v.x;
    d1[0] += ba.x * v.y; d1[1] += ba.y * v.y; d1[2] += ba.z * v.y; d1[3] += ba.w * v.y;
    d1[4] += bb.x * v.y; d1[5] += bb.y * v.y; d1[6] += bb.z * v.y; d1[7] += bb.w * v.y;
  }

  const float rn0 = 1.0f / fmaxf(sqrtf(ss0), 1e-12f);
  const float rn1 = 1.0f / fmaxf(sqrtf(ss1), 1e-12f);
  float m0 = -3e38f, m1 = -3e38f;
#pragma unroll
  for (int k = 0; k < 8; ++k) {
    d0[k] *= rn0; d1[k] *= rn1;
    if (s_vld[k] > 0.5f) { m0 = fmaxf(m0, d0[k]); m1 = fmaxf(m1, d1[k]); }
  }
  float a0[8], a1[8];
  float sum0 = 0.f, sum1 = 0.f;
#pragma unroll
  for (int k = 0; k < 8; ++k) {
    const float e0 = (s_vld[k] > 0.5f) ? __expf(d0[k] - m0) : 0.f;
    const float e1 = (s_vld[k] > 0.5f) ? __expf(d1[k] - m1) : 0.f;
    a0[k] = e0; a1[k] = e1; sum0 += e0; sum1 += e1;
  }
  const float i0 = (sum0 > 0.f) ? 1.0f / sum0 : 0.f;   // 0 => no valid slot => attn 0
  const float i1 = (sum1 > 0.f) ? 1.0f / sum1 : 0.f;
#pragma unroll
  for (int k = 0; k < 8; ++k) { a0[k] *= i0; a1[k] *= i1; }

  // pass 2: blend and store (value re-read should be L2/L3-hot)
#pragma unroll 4
  for (int c = 0; c < Cc; ++c) {
    const float2 v = v2[c * HW2 + p2];
    const float2 f = f2[c * HW2 + p2];
    const float4 pa = pn4[c * 2 + 0];
    const float4 pb = pn4[c * 2 + 1];
    const float pm0 = a0[0] * pa.x + a0[1] * pa.y + a0[2] * pa.z + a0[3] * pa.w +
                      a0[4] * pb.x + a0[5] * pb.y + a0[6] * pb.z + a0[7] * pb.w;
    const float pm1 = a1[0] * pa.x + a1[1] * pa.y + a1[2] * pa.z + a1[3] * pa.w +
                      a1[4] * pb.x + a1[5] * pb.y + a1[6] * pb.z + a1[7] * pb.w;
    float2 o;
    o.x = v.x + pg * pm0 + fg * f.x;
    o.y = v.y + pg * pm1 + fg * f.y;
    o2[c * HW2 + p2] = o;
  }
}

// ---------------- launch ---------------------------------------------------
extern "C" void kernel_launch(void* const* d_in, const int* in_sizes, int n_in,
                              void* d_out, int out_size, void* d_ws, size_t ws_size,
                              hipStream_t stream) {
  const float* value = (const float*)d_in[0];
  const float* frame = (const float*)d_in[1];
  const float* mask  = (const float*)d_in[2];
  const float* proto = (const float*)d_in[3];
  const float* age   = (const float*)d_in[4];
  const float* usage = (const float*)d_in[5];
  const float* conf  = (const float*)d_in[6];
  // d_in[7..10] = W1,b1,W2,b2 — dead code in the reference (logits unused)
  const float* pg = (const float*)d_in[11];
  const float* fg = (const float*)d_in[12];
  const int* valid = (const int*)d_in[13];
  float* out = (float*)d_out;

  float* w = (float*)d_ws;
  float* sum_v     = w;                  // BN*Cc      = 4096
  float* sum_vm    = w + 4096;           // BN*Cc      = 4096
  float* proto_new = w + 8192;           // BN*Kc*Cc   = 32768
  float* bank_nn   = w + 40960;          // BN*Kc*Cc   = 32768
  float* validf    = w + 73728;          // BN*Kc      = 128

  hipLaunchKernelGGL(k1_sums, dim3(BN * Cc), dim3(256), 0, stream,
                     value, mask, sum_v, sum_vm);
  hipLaunchKernelGGL(k2_update, dim3(BN), dim3(256), 0, stream,
                     mask, proto, age, usage, conf, valid, sum_v, sum_vm,
                     proto_new, bank_nn, validf);
  hipLaunchKernelGGL(k3_readout, dim3(BN * 36), dim3(128), 0, stream,
                     value, frame, proto_new, bank_nn, validf, pg, fg, out);
}

// Round 2
// 387.868 us; speedup vs baseline: 1.1387x; 1.1387x over previous
//
#include <hip/hip_runtime.h>
#include <math.h>

// Problem constants (B,N,K,C,H,W) = (2,8,8,256,96,96)
constexpr int Bc = 2, Nc = 8, Kc = 8, Cc = 256, HWc = 96 * 96;   // HW = 9216
constexpr int BN = Bc * Nc;                                       // 16
constexpr int HW2 = HWc / 2;                                      // 4608 float2
constexpr float ALPHA = 0.3f;
constexpr float SIM_HIGH = 0.8f, SIM_LOW = 0.3f;

// ---------------- reduction helpers ----------------------------------------
__device__ __forceinline__ float wred_sum_all(float v) {   // butterfly, all lanes
#pragma unroll
  for (int o = 32; o > 0; o >>= 1) v += __shfl_xor(v, o, 64);
  return v;
}
__device__ __forceinline__ float wred_sum(float v) {
#pragma unroll
  for (int o = 32; o > 0; o >>= 1) v += __shfl_down(v, o, 64);
  return v;
}
__device__ __forceinline__ float wred_max(float v) {
#pragma unroll
  for (int o = 32; o > 0; o >>= 1) v = fmaxf(v, __shfl_down(v, o, 64));
  return v;
}
__device__ __forceinline__ float bred_sum(float v, float* sc) {
  int lane = threadIdx.x & 63, wid = threadIdx.x >> 6;
  v = wred_sum(v);
  __syncthreads();
  if (lane == 0) sc[wid] = v;
  __syncthreads();
  return sc[0] + sc[1] + sc[2] + sc[3];
}
__device__ __forceinline__ float bred_max(float v, float* sc) {
  int lane = threadIdx.x & 63, wid = threadIdx.x >> 6;
  v = wred_max(v);
  __syncthreads();
  if (lane == 0) sc[wid] = v;
  __syncthreads();
  return fmaxf(fmaxf(sc[0], sc[1]), fmaxf(sc[2], sc[3]));
}

// ---------------- K1: per-(b,n,c) sums of value and value*mask -------------
__global__ __launch_bounds__(256) void k1_sums(const float* __restrict__ value,
                                               const float* __restrict__ mask,
                                               float* __restrict__ sum_v,
                                               float* __restrict__ sum_vm) {
  const int bnc = blockIdx.x;      // (b*N+n)*C + c
  const int bn = bnc >> 8;
  const int tid = threadIdx.x;
  const float4* v4 = (const float4*)(value + (size_t)bnc * HWc);
  const float4* m4 = (const float4*)(mask + (size_t)bn * HWc);
  float av = 0.f, avm = 0.f;
#pragma unroll
  for (int i = 0; i < 9; ++i) {              // 9*256*4 = 9216
    float4 v = v4[i * 256 + tid];
    float4 m = m4[i * 256 + tid];
    av += v.x + v.y + v.z + v.w;
    avm += v.x * m.x + v.y * m.y + v.z * m.z + v.w * m.w;
  }
  __shared__ float sc[8];
  float rv = wred_sum(av);
  float rvm = wred_sum(avm);
  int lane = tid & 63, wid = tid >> 6;
  if (lane == 0) { sc[wid] = rv; sc[4 + wid] = rvm; }
  __syncthreads();
  if (tid == 0) {
    sum_v[bnc] = sc[0] + sc[1] + sc[2] + sc[3];
    sum_vm[bnc] = sc[4] + sc[5] + sc[6] + sc[7];
  }
}

// ---------------- K2: control logic + bank update (1 block per (b,n)) ------
// Wave-parallel: wave w owns k = w and k = w+4.
__global__ __launch_bounds__(256) void k2_update(
    const float* __restrict__ mask, const float* __restrict__ proto,
    const float* __restrict__ age, const float* __restrict__ usage,
    const float* __restrict__ conf, const int* __restrict__ valid,
    const float* __restrict__ sum_v, const float* __restrict__ sum_vm,
    float* __restrict__ proto_new, float* __restrict__ bank_nn,
    float* __restrict__ validf) {
  const int bn = blockIdx.x;
  const int tid = threadIdx.x;
  const int lane = tid & 63, w = tid >> 6;
  __shared__ float sc[4];
  __shared__ float s_cand[Cc];
  __shared__ float s_sim[Kc];
  __shared__ int s_slot, s_ref, s_wr;

  // global maxima for age_n / usage_n (over all B,N,K = 128 values)
  float a = (tid < BN * Kc) ? age[tid] : -3e38f;
  float u = (tid < BN * Kc) ? usage[tid] : -3e38f;
  const float age_den = fmaxf(bred_max(a, sc), 1.0f);
  const float usage_den = fmaxf(bred_max(u, sc), 1.0f);

  // mask sum for this (b,n)
  float ms = 0.f;
  const float* mrow = mask + (size_t)bn * HWc;
  for (int i = tid; i < HWc; i += 256) ms += mrow[i];
  const float msum = bred_sum(ms, sc);
  const float denom = fmaxf(msum, 1e-6f);

  // candidate prototype (c = tid), l2-normalized
  const int c = tid;
  const float sv = sum_v[bn * Cc + c];
  const float svm = sum_vm[bn * Cc + c];
  float cand = (denom <= 1e-5f) ? (sv * (1.0f / HWc)) : (svm / denom);
  const float css = bred_sum(cand * cand, sc);
  s_cand[c] = cand / fmaxf(sqrtf(css), 1e-12f);
  __syncthreads();

  const float4* cand4 = (const float4*)s_cand;
  const float4 c4 = cand4[lane];

  // sims: wave w handles k = w, w+4 (no block syncs)
#pragma unroll
  for (int kk = 0; kk < 2; ++kk) {
    const int k = w + kk * 4;
    const float4 p4 = ((const float4*)(proto + ((size_t)bn * Kc + k) * Cc))[lane];
    const float pss = wred_sum_all(p4.x * p4.x + p4.y * p4.y + p4.z * p4.z + p4.w * p4.w);
    const float pd  = wred_sum_all(p4.x * c4.x + p4.y * c4.y + p4.z * c4.z + p4.w * c4.w);
    if (lane == 0)
      s_sim[k] = (valid[bn * Kc + k] != 0) ? (pd / fmaxf(sqrtf(pss), 1e-12f)) : -1.0f;
  }
  __syncthreads();

  if (tid == 0) {
    bool anyv = false;
    for (int k = 0; k < Kc; ++k) anyv = anyv || (valid[bn * Kc + k] != 0);
    int tslot = 0; float best = s_sim[0];
    for (int k = 1; k < Kc; ++k)
      if (s_sim[k] > best) { best = s_sim[k]; tslot = k; }   // first max
    const float max_sim = anyv ? best : -1.0f;
    const int action = (!anyv) ? 3 : (max_sim >= SIM_HIGH ? 1 : (max_sim >= SIM_LOW ? 0 : 3));
    int victim = 0; float vb = -3e38f;
    for (int k = 0; k < Kc; ++k) {
      const float s = age[bn * Kc + k] / age_den + (1.f - usage[bn * Kc + k] / usage_den) +
                      (1.f - conf[bn * Kc + k]);
      if (s > vb) { vb = s; victim = k; }
    }
    int fe = 0; bool hasE = false;
    for (int k = 0; k < Kc; ++k)
      if (valid[bn * Kc + k] == 0) { fe = k; hasE = true; break; }
    const int spawn = hasE ? fe : victim;
    s_slot = (action == 1) ? tslot : spawn;
    s_ref = (action == 1);
    s_wr = (action == 3);
  }
  __syncthreads();

  // bank update + pre-normalized bank (wave-parallel, branches wave-uniform)
#pragma unroll
  for (int kk = 0; kk < 2; ++kk) {
    const int k = w + kk * 4;
    const float4 p4 = ((const float4*)(proto + ((size_t)bn * Kc + k) * Cc))[lane];
    float4 pn;
    if (k == s_slot && s_ref) {
      float4 t;
      t.x = (1.0f - ALPHA) * p4.x + ALPHA * c4.x;
      t.y = (1.0f - ALPHA) * p4.y + ALPHA * c4.y;
      t.z = (1.0f - ALPHA) * p4.z + ALPHA * c4.z;
      t.w = (1.0f - ALPHA) * p4.w + ALPHA * c4.w;
      const float tss = wred_sum_all(t.x * t.x + t.y * t.y + t.z * t.z + t.w * t.w);
      const float inv = 1.0f / fmaxf(sqrtf(tss), 1e-12f);
      pn.x = t.x * inv; pn.y = t.y * inv; pn.z = t.z * inv; pn.w = t.w * inv;
    } else if (k == s_slot && s_wr) {
      pn = c4;
    } else {
      pn = p4;
    }
    ((float4*)(proto_new + ((size_t)bn * Kc + k) * Cc))[lane] = pn;
    const float bss = wred_sum_all(pn.x * pn.x + pn.y * pn.y + pn.z * pn.z + pn.w * pn.w);
    const float binv = 1.0f / fmaxf(sqrtf(bss), 1e-12f);
    float4 bnv;
    bnv.x = pn.x * binv; bnv.y = pn.y * binv; bnv.z = pn.z * binv; bnv.w = pn.w * binv;
    ((float4*)(bank_nn + ((size_t)bn * Kc + k) * Cc))[lane] = bnv;
  }
  if (tid < Kc) {
    const int k = tid;
    const int vn = (valid[bn * Kc + k] != 0) || (s_wr && k == s_slot);
    validf[bn * Kc + k] = vn ? 1.0f : 0.0f;
  }
}

// ---------------- K3: readout (softmax-attention blend) --------------------
// block = 256 threads = 4 waves; wave w owns channels [64w,64w+64) for the
// SAME 128 positions (float2 per lane). Grid = BN * 72 = 1152 blocks.
__global__ __launch_bounds__(256) void k3_readout(
    const float* __restrict__ value, const float* __restrict__ frame,
    const float* __restrict__ proto_new, const float* __restrict__ bank_nn,
    const float* __restrict__ validf, const float* __restrict__ pgp,
    const float* __restrict__ fgp, float* __restrict__ out) {
  const int bn = blockIdx.x / 72;
  const int tile = blockIdx.x % 72;
  const int b = bn >> 3;
  const int tid = threadIdx.x;
  const int lane = tid & 63, w = tid >> 6;
  const int p2 = tile * 64 + lane;           // float2 index within HW2

  __shared__ float s_bank[Kc * Cc];          // [c][k]  8 KB
  __shared__ float s_pn[Kc * Cc];            // [c][k]  8 KB
  __shared__ float s_part[4][9][128];        // [w][8 dots + ss][pos] 18 KB
  __shared__ float s_attn[Kc][128];          // [k][pos] 4 KB
  __shared__ float s_vld[Kc];

  const float* bsrc = bank_nn + (size_t)bn * Kc * Cc;
  const float* psrc = proto_new + (size_t)bn * Kc * Cc;
  for (int i = tid; i < Kc * Cc; i += 256) {
    const int k = i >> 8, c = i & 255;
    s_bank[c * 8 + k] = bsrc[i];
    s_pn[c * 8 + k] = psrc[i];
  }
  if (tid < Kc) s_vld[tid] = validf[bn * Kc + tid];
  __syncthreads();

  const float pg = pgp[0], fg = fgp[0];
  const float2* v2 = (const float2*)(value + (size_t)bn * Cc * HWc);
  const float2* f2 = (const float2*)(frame + (size_t)b * Cc * HWc);
  float2* o2 = (float2*)(out + (size_t)bn * Cc * HWc);
  const float4* bk4 = (const float4*)s_bank;
  const float4* pn4 = (const float4*)s_pn;

  // ---- pass 1: partial dots + partial squared-norm over this wave's 64 c --
  float ss0 = 0.f, ss1 = 0.f;
  float d0[8], d1[8];
#pragma unroll
  for (int k = 0; k < 8; ++k) { d0[k] = 0.f; d1[k] = 0.f; }

#pragma unroll 8
  for (int c0 = 0; c0 < 64; ++c0) {
    const int c = (w << 6) + c0;
    const float2 v = v2[c * HW2 + p2];
    const float4 ba = bk4[c * 2 + 0];        // wave-uniform -> broadcast
    const float4 bb = bk4[c * 2 + 1];
    ss0 += v.x * v.x; ss1 += v.y * v.y;
    d0[0] += ba.x * v.x; d0[1] += ba.y * v.x; d0[2] += ba.z * v.x; d0[3] += ba.w * v.x;
    d0[4] += bb.x * v.x; d0[5] += bb.y * v.x; d0[6] += bb.z * v.x; d0[7] += bb.w * v.x;
    d1[0] += ba.x * v.y; d1[1] += ba.y * v.y; d1[2] += ba.z * v.y; d1[3] += ba.w * v.y;
    d1[4] += bb.x * v.y; d1[5] += bb.y * v.y; d1[6] += bb.z * v.y; d1[7] += bb.w * v.y;
  }
  // write partials (float2 per lane: stride-2-float => 2-way alias, free)
#pragma unroll
  for (int k = 0; k < 8; ++k)
    ((float2*)&s_part[w][k][0])[lane] = make_float2(d0[k], d1[k]);
  ((float2*)&s_part[w][8][0])[lane] = make_float2(ss0, ss1);
  __syncthreads();

  // ---- cross-group reduce + softmax (one thread per position) -------------
  if (tid < 128) {
    float dd[9];
#pragma unroll
    for (int j = 0; j < 9; ++j)
      dd[j] = s_part[0][j][tid] + s_part[1][j][tid] + s_part[2][j][tid] + s_part[3][j][tid];
    const float rn = 1.0f / fmaxf(sqrtf(dd[8]), 1e-12f);
    float m = -3e38f;
#pragma unroll
    for (int k = 0; k < 8; ++k) {
      dd[k] *= rn;
      if (s_vld[k] > 0.5f) m = fmaxf(m, dd[k]);
    }
    float e[8], sum = 0.f;
#pragma unroll
    for (int k = 0; k < 8; ++k) {
      e[k] = (s_vld[k] > 0.5f) ? __expf(dd[k] - m) : 0.f;
      sum += e[k];
    }
    const float inv = (sum > 0.f) ? 1.0f / sum : 0.f;   // no valid slot -> attn 0
#pragma unroll
    for (int k = 0; k < 8; ++k) s_attn[k][tid] = e[k] * inv;
  }
  __syncthreads();

  float a0[8], a1[8];
#pragma unroll
  for (int k = 0; k < 8; ++k) {
    const float2 t = ((const float2*)&s_attn[k][0])[lane];
    a0[k] = t.x; a1[k] = t.y;
  }

  // ---- pass 2: blend this wave's 64 channels (re-read is L2/L3-hot) -------
#pragma unroll 4
  for (int c0 = 0; c0 < 64; ++c0) {
    const int c = (w << 6) + c0;
    const float2 v = v2[c * HW2 + p2];
    const float2 f = f2[c * HW2 + p2];
    const float4 pa = pn4[c * 2 + 0];
    const float4 pb = pn4[c * 2 + 1];
    const float pm0 = a0[0] * pa.x + a0[1] * pa.y + a0[2] * pa.z + a0[3] * pa.w +
                      a0[4] * pb.x + a0[5] * pb.y + a0[6] * pb.z + a0[7] * pb.w;
    const float pm1 = a1[0] * pa.x + a1[1] * pa.y + a1[2] * pa.z + a1[3] * pa.w +
                      a1[4] * pb.x + a1[5] * pb.y + a1[6] * pb.z + a1[7] * pb.w;
    float2 o;
    o.x = v.x + pg * pm0 + fg * f.x;
    o.y = v.y + pg * pm1 + fg * f.y;
    o2[c * HW2 + p2] = o;
  }
}

// ---------------- launch ---------------------------------------------------
extern "C" void kernel_launch(void* const* d_in, const int* in_sizes, int n_in,
                              void* d_out, int out_size, void* d_ws, size_t ws_size,
                              hipStream_t stream) {
  const float* value = (const float*)d_in[0];
  const float* frame = (const float*)d_in[1];
  const float* mask  = (const float*)d_in[2];
  const float* proto = (const float*)d_in[3];
  const float* age   = (const float*)d_in[4];
  const float* usage = (const float*)d_in[5];
  const float* conf  = (const float*)d_in[6];
  // d_in[7..10] = W1,b1,W2,b2 — dead code in the reference (logits unused)
  const float* pg = (const float*)d_in[11];
  const float* fg = (const float*)d_in[12];
  const int* valid = (const int*)d_in[13];
  float* out = (float*)d_out;

  float* w = (float*)d_ws;
  float* sum_v     = w;                  // BN*Cc      = 4096
  float* sum_vm    = w + 4096;           // BN*Cc      = 4096
  float* proto_new = w + 8192;           // BN*Kc*Cc   = 32768
  float* bank_nn   = w + 40960;          // BN*Kc*Cc   = 32768
  float* validf    = w + 73728;          // BN*Kc      = 128

  hipLaunchKernelGGL(k1_sums, dim3(BN * Cc), dim3(256), 0, stream,
                     value, mask, sum_v, sum_vm);
  hipLaunchKernelGGL(k2_update, dim3(BN), dim3(256), 0, stream,
                     mask, proto, age, usage, conf, valid, sum_v, sum_vm,
                     proto_new, bank_nn, validf);
  hipLaunchKernelGGL(k3_readout, dim3(BN * 72), dim3(256), 0, stream,
                     value, frame, proto_new, bank_nn, validf, pg, fg, out);
}